// Round 8
// baseline (239.897 us; speedup 1.0000x reference)
//
#include <hip/hip_runtime.h>
#include <hip/hip_bf16.h>

#define NB   8
#define NS   5
#define TT   16
#define DD   2048
#define NROW 1024               // B*nq
#define NSROW 640               // supp rows
#define TILESH (TT * DD)        // 32768 shorts per packed 16x2048 tile
#define LDH  1032               // half-tile LDS row stride in shorts (+8 pad)
#define LAMI 10.0f
#define LAMF 0.1f

typedef __attribute__((ext_vector_type(8))) short  short8;
typedef __attribute__((ext_vector_type(4))) float  float4v;

// single-instruction packed f32x2 -> bf16x2 (RNE), lo = x
static __device__ __forceinline__ unsigned int cvtpk(float x, float y) {
    unsigned int r;
    asm("v_cvt_pk_bf16_f32 %0, %1, %2" : "=v"(r) : "v"(x), "v"(y));
    return r;
}

// lane i <- lane i-1 across the whole wave (lane 0 <- 0). 1 VALU op, no LDS.
static __device__ __forceinline__ float dpp_shr1(float x) {
    int r = __builtin_amdgcn_update_dpp(0, __builtin_bit_cast(int, x),
                                        0x138 /*wave_shr:1*/, 0xF, 0xF, true);
    return __builtin_bit_cast(float, r);
}

// ---- shared tail (verified R5-R7): DTW 12 lane-groups + tam + fused CE ----
static __device__ __forceinline__ void
dtw_and_out(const float (*distS)[TT][TT], float* tamv, int tid, int blk,
            const int* __restrict__ ys, float* __restrict__ out)
{
    const int wave = tid >> 6, lane = tid & 63;
    {
        const int grp  = lane / 21;             // 3 => unused tail lanes
        const int g    = lane - grp * 21;       // 0..20 within group
        const int slot = wave * 3 + grp;        // s*2+dir
        float val = 0.f, vprev = 0.f;           // init ALL lanes (dpp sources)
        if (grp < 3 && slot < 10 && g <= 17) {
            const int s    = slot >> 1;
            const int dir  = slot & 1;
            const bool isb = (g == 1) | (g == 17);
            #pragma unroll
            for (int t = 1; t <= 32; ++t) {
                float left = dpp_shr1(val);
                float diag = dpp_shr1(vprev);
                int l = t - g;
                if (g >= 1 && l >= 0 && l <= 15) {
                    float d = 0.f;
                    if (g <= 16) d = dir ? distS[s][15 - l][16 - g] : distS[s][l][g - 1];
                    float nv;
                    if (l == 0) {
                        nv = left + d;
                    } else {
                        float am = -LAMI * diag, bm = -LAMI * left;
                        float mx = fmaxf(am, bm);
                        float s3 = 0.f;
                        if (isb) {
                            float cm = -LAMI * val;
                            float m3 = fmaxf(mx, cm);
                            s3 = __expf(cm - m3);
                            mx = m3;
                        }
                        float ssum = __expf(am - mx) + __expf(bm - mx) + s3;
                        nv = fmaf(-LAMF, mx + __logf(ssum), d);
                    }
                    vprev = val; val = nv;
                }
            }
            if (g == 17) tamv[slot] = val;
        }
    }
    __syncthreads();

    if (tid < NS) out[1 + blk * NS + tid] = 0.5f * (tamv[2 * tid] + tamv[2 * tid + 1]);
    if (tid == 0) {
        float t1v[NS], t2v[NS];
        #pragma unroll
        for (int s = 0; s < NS; ++s) { t1v[s] = tamv[2 * s]; t2v[s] = tamv[2 * s + 1]; }
        const int y = ys[blk];
        float mx1 = -t1v[0], mx2 = -t2v[0];
        #pragma unroll
        for (int s = 1; s < NS; ++s) { mx1 = fmaxf(mx1, -t1v[s]); mx2 = fmaxf(mx2, -t2v[s]); }
        float s1 = 0.f, s2 = 0.f;
        #pragma unroll
        for (int s = 0; s < NS; ++s) { s1 += __expf(-t1v[s] - mx1); s2 += __expf(-t2v[s] - mx2); }
        float lse1  = mx1 + __logf(s1);
        float lse2v = mx2 + __logf(s2);
        float ty1 = t1v[0], ty2 = t2v[0];
        #pragma unroll
        for (int s = 1; s < NS; ++s) { if (y == s) { ty1 = t1v[s]; ty2 = t2v[s]; } }
        float c = 0.5f * ((lse1 + ty1) + (lse2v + ty2));
        atomicAdd(out, c * (1.0f / (float)NROW));
    }
}

// Supp pack (R6/R7-verified): normalize row, cvt bf16, store MFMA-fragment
// order: element (row fr, k=kk*32+c*8+j) -> tile + kk*512 + (c*16+fr)*8 + j.
// 2.6 MB scatter-write is ~2 us — negligible (the 66 MB query version wasn't).
__global__ __launch_bounds__(256) void
pack_supp(const float* __restrict__ supp, unsigned short* __restrict__ sPk,
          float* __restrict__ loss0)
{
    if (blockIdx.x == 0 && threadIdx.x == 0) loss0[0] = 0.f;
    const int wave = threadIdx.x >> 6, lane = threadIdx.x & 63;
    const int row = blockIdx.x * 4 + wave;           // 0..639
    const float* src = supp + (size_t)row * DD;
    unsigned short* dstTile = sPk + (size_t)(row >> 4) * TILESH;   // tile = b*NS+s
    const int fr = row & 15;

    float4 v[4][2];
    float ss = 0.f;
    #pragma unroll
    for (int it = 0; it < 4; ++it) {
        v[it][0] = *reinterpret_cast<const float4*>(src + it * 512 + lane * 8);
        v[it][1] = *reinterpret_cast<const float4*>(src + it * 512 + lane * 8 + 4);
        #pragma unroll
        for (int h = 0; h < 2; ++h)
            ss += v[it][h].x * v[it][h].x + v[it][h].y * v[it][h].y
                + v[it][h].z * v[it][h].z + v[it][h].w * v[it][h].w;
    }
    #pragma unroll
    for (int off = 32; off >= 1; off >>= 1) ss += __shfl_xor(ss, off, 64);
    const float rs = 1.0f / sqrtf(fmaxf(ss, 1e-16f));

    #pragma unroll
    for (int it = 0; it < 4; ++it) {
        uint4 pv;
        pv.x = cvtpk(v[it][0].x * rs, v[it][0].y * rs);
        pv.y = cvtpk(v[it][0].z * rs, v[it][0].w * rs);
        pv.z = cvtpk(v[it][1].x * rs, v[it][1].y * rs);
        pv.w = cvtpk(v[it][1].z * rs, v[it][1].w * rs);
        const int kk = it * 16 + (lane >> 2);   // k/32
        const int c  = lane & 3;                // (k%32)/8
        *reinterpret_cast<uint4*>(dstTile + kk * 512 + (c * 16 + fr) * 8) = pv;
    }
}

// One block per (b,q), 4 waves. Query staged in TWO 1024-col halves (33 KB
// buffer, R1's verified pattern) -> LDS ~33.2 KB -> 4 blocks/CU (the R7
// occupancy fix). Per half: stage (coalesced f32 reads, cvt, ds_write, reg
// sumsq) -> bar -> K-loop (wave w owns cols w*256..+255 of the half; A from
// packed sPk = coalesced 1KB wave-loads, R6-verified; 5 MFMA/kk) -> bar.
// acc persists across halves (R5 scheme). After K: overlay red/distS into the
// dead tile (R7 trick), reduce, divide by q-norm, DTW tail, fused CE.
__global__ __launch_bounds__(256, 4) void
dist_dtw_f2(const unsigned short* __restrict__ sPk, const float* __restrict__ query,
            const int* __restrict__ ys, float* __restrict__ out)
{
    __shared__ __align__(16) unsigned char smem[TT * LDH * 2];   // 33024 B
    unsigned short (*sB)[LDH] = reinterpret_cast<unsigned short(*)[LDH]>(smem);
    // overlay (valid only after the final K-loop barrier):
    float (*red)[NS][64][4] = reinterpret_cast<float(*)[NS][64][4]>(smem);      // 20480 B
    float (*distS)[TT][TT]  = reinterpret_cast<float(*)[TT][TT]>(smem + 20480); //  5120 B
    __shared__ float qq[16];
    __shared__ float tamv[12];

    const int tid  = threadIdx.x;
    const int blk  = blockIdx.x;          // b*128 + q
    const int wave = tid >> 6;            // 0..3
    const int lane = tid & 63;
    const int fr   = lane & 15;
    const int quad = lane >> 4;

    float4v acc[NS];
    #pragma unroll
    for (int s = 0; s < NS; ++s) acc[s] = (float4v){0.f, 0.f, 0.f, 0.f};
    float qs[4] = {0.f, 0.f, 0.f, 0.f};   // per-row sumsq partials (rows wave*4+j)

    const unsigned short* spBase = sPk + (size_t)(blk >> 7) * NS * TILESH + lane * 8;

    #pragma unroll
    for (int h = 0; h < 2; ++h) {
        // ---- stage half h: wave w stages rows 4w..4w+3, cols h*1024..+1023 ----
        #pragma unroll
        for (int j = 0; j < 4; ++j) {
            const int r = wave * 4 + j;
            const float* src = query + (size_t)(blk * TT + r) * DD + h * 1024;
            #pragma unroll
            for (int i = 0; i < 2; ++i) {
                float4 v0 = *reinterpret_cast<const float4*>(src + i * 512 + lane * 8);
                float4 v1 = *reinterpret_cast<const float4*>(src + i * 512 + lane * 8 + 4);
                uint4 pv = { cvtpk(v0.x, v0.y), cvtpk(v0.z, v0.w),
                             cvtpk(v1.x, v1.y), cvtpk(v1.z, v1.w) };
                *reinterpret_cast<uint4*>(&sB[r][i * 512 + lane * 8]) = pv;
                qs[j] += v0.x*v0.x + v0.y*v0.y + v0.z*v0.z + v0.w*v0.w
                       + v1.x*v1.x + v1.y*v1.y + v1.z*v1.z + v1.w*v1.w;
            }
        }
        __syncthreads();

        // ---- K-loop on half h: wave w owns local cols w*256 .. w*256+255 ----
        const unsigned short* bb = &sB[fr][wave * 256 + quad * 8];
        #pragma unroll
        for (int kk = 0; kk < 8; ++kk) {
            short8 b = *reinterpret_cast<const short8*>(bb + kk * 32);
            const int kkg = h * 32 + wave * 8 + kk;   // global k/32 index
            #pragma unroll
            for (int s = 0; s < NS; ++s) {
                short8 a = *reinterpret_cast<const short8*>(
                    spBase + (size_t)s * TILESH + (size_t)kkg * 512);
                acc[s] = __builtin_amdgcn_mfma_f32_16x16x32_bf16(a, b, acc[s], 0, 0, 0);
            }
        }
        __syncthreads();   // all reads of sB done (half 0: before re-stage;
                           // half 1: before the red overlay below)
    }

    // ---- overlay writes: 4 wave-partials + q row norms ----
    #pragma unroll
    for (int s = 0; s < NS; ++s)
        *reinterpret_cast<float4v*>(red[wave][s][lane]) = acc[s];
    #pragma unroll
    for (int j = 0; j < 4; ++j) {
        float ss = qs[j];
        #pragma unroll
        for (int off = 32; off >= 1; off >>= 1) ss += __shfl_xor(ss, off, 64);
        if (lane == 0) qq[wave * 4 + j] = ss;
    }
    __syncthreads();

    // ---- reduce partials; dist = 1 - dot/||q|| (supp pre-normalized) ----
    for (int p = tid; p < NS * 64; p += 256) {
        int t = p >> 6, ln = p & 63;
        float4v s4 = *reinterpret_cast<const float4v*>(red[0][t][ln]);
        #pragma unroll
        for (int w = 1; w < 4; ++w) {
            float4v r = *reinterpret_cast<const float4v*>(red[w][t][ln]);
            s4[0] += r[0]; s4[1] += r[1]; s4[2] += r[2]; s4[3] += r[3];
        }
        int m = ln & 15, qd = ln >> 4;
        float rq = 1.0f / sqrtf(fmaxf(qq[m], 1e-16f));
        #pragma unroll
        for (int r = 0; r < 4; ++r) distS[t][qd * 4 + r][m] = 1.0f - s4[r] * rq;
    }
    __syncthreads();

    dtw_and_out(distS, tamv, tid, blk, ys, out);
}

extern "C" void kernel_launch(void* const* d_in, const int* in_sizes, int n_in,
                              void* d_out, int out_size, void* d_ws, size_t ws_size,
                              hipStream_t stream) {
    const float* supp  = (const float*)d_in[0];
    const float* query = (const float*)d_in[1];
    const int*   ys    = (const int*)d_in[2];
    float* out = (float*)d_out;

    // workspace: packed supp tiles only — 40 * 32768 shorts = 2.62 MB
    unsigned short* sPk = (unsigned short*)d_ws;

    pack_supp<<<NSROW / 4, 256, 0, stream>>>(supp, sPk, out);
    dist_dtw_f2<<<NROW, 256, 0, stream>>>(sPk, query, ys, out);
}

// Round 9
// 218.625 us; speedup vs baseline: 1.0973x; 1.0973x over previous
//
#include <hip/hip_runtime.h>
#include <hip/hip_bf16.h>

#define NB   8
#define NS   5
#define TT   16
#define DD   2048
#define NROW 1024               // B*nq
#define NSROW 640               // supp rows
#define TILESH (TT * DD)        // 32768 shorts per packed 16x2048 tile
#define LDH  1032               // half-tile LDS row stride in shorts (+8 pad)
#define LAMI 10.0f
#define LAMF 0.1f

typedef __attribute__((ext_vector_type(8))) short  short8;
typedef __attribute__((ext_vector_type(4))) float  float4v;

// single-instruction packed f32x2 -> bf16x2 (RNE), lo = x
static __device__ __forceinline__ unsigned int cvtpk(float x, float y) {
    unsigned int r;
    asm("v_cvt_pk_bf16_f32 %0, %1, %2" : "=v"(r) : "v"(x), "v"(y));
    return r;
}

// lane i <- lane i-1 across the whole wave (lane 0 <- 0). 1 VALU op, no LDS.
static __device__ __forceinline__ float dpp_shr1(float x) {
    int r = __builtin_amdgcn_update_dpp(0, __builtin_bit_cast(int, x),
                                        0x138 /*wave_shr:1*/, 0xF, 0xF, true);
    return __builtin_bit_cast(float, r);
}

// ---- 512-thread tail (verified R4): DTW wave s lanes 0..17 / 32..49 + CE ----
static __device__ __forceinline__ void
dtw_tail512(const float (*distS)[TT][TT], float* tamv, int tid, int blk,
            const int* __restrict__ ys, float* __restrict__ out)
{
    const int wave = tid >> 6, lane = tid & 63;
    if (wave < NS && (lane & 31) <= 17) {
        const int g    = lane & 31;
        const int dir  = lane >> 5;
        const int s    = wave;
        const bool isb = (g == 1) | (g == 17);   // band-edge: 3-way softmin
        float val = 0.f, vprev = 0.f;
        #pragma unroll
        for (int t = 1; t <= 32; ++t) {
            float left = dpp_shr1(val);
            float diag = dpp_shr1(vprev);
            int l = t - g;
            if (g >= 1 && l >= 0 && l <= 15) {
                float d = 0.f;
                if (g <= 16) d = dir ? distS[s][15 - l][16 - g] : distS[s][l][g - 1];
                float nv;
                if (l == 0) {
                    nv = left + d;
                } else {
                    float am = -LAMI * diag, bm = -LAMI * left;
                    float mx = fmaxf(am, bm);
                    float s3 = 0.f;
                    if (isb) {
                        float cm = -LAMI * val;
                        float m3 = fmaxf(mx, cm);
                        s3 = __expf(cm - m3);
                        mx = m3;
                    }
                    float ssum = __expf(am - mx) + __expf(bm - mx) + s3;
                    nv = fmaf(-LAMF, mx + __logf(ssum), d);
                }
                vprev = val; val = nv;
            }
        }
        if (g == 17) tamv[s * 2 + dir] = val;
    }
    __syncthreads();

    if (tid < NS) out[1 + blk * NS + tid] = 0.5f * (tamv[2 * tid] + tamv[2 * tid + 1]);
    if (tid == 0) {
        float t1v[NS], t2v[NS];
        #pragma unroll
        for (int s = 0; s < NS; ++s) { t1v[s] = tamv[2 * s]; t2v[s] = tamv[2 * s + 1]; }
        const int y = ys[blk];
        float mx1 = -t1v[0], mx2 = -t2v[0];
        #pragma unroll
        for (int s = 1; s < NS; ++s) { mx1 = fmaxf(mx1, -t1v[s]); mx2 = fmaxf(mx2, -t2v[s]); }
        float s1 = 0.f, s2 = 0.f;
        #pragma unroll
        for (int s = 0; s < NS; ++s) { s1 += __expf(-t1v[s] - mx1); s2 += __expf(-t2v[s] - mx2); }
        float lse1  = mx1 + __logf(s1);
        float lse2v = mx2 + __logf(s2);
        float ty1 = t1v[0], ty2 = t2v[0];
        #pragma unroll
        for (int s = 1; s < NS; ++s) { if (y == s) { ty1 = t1v[s]; ty2 = t2v[s]; } }
        float c = 0.5f * ((lse1 + ty1) + (lse2v + ty2));
        atomicAdd(out, c * (1.0f / (float)NROW));
    }
}

// Supp pack (verified R6/R7/R8): normalize row, cvt bf16, store MFMA-fragment
// order: element (row fr, k) -> tile + (k/32)*512 + (((k%32)/8)*16 + fr)*8 + k%8.
__global__ __launch_bounds__(256) void
pack_supp(const float* __restrict__ supp, unsigned short* __restrict__ sPk,
          float* __restrict__ loss0)
{
    if (blockIdx.x == 0 && threadIdx.x == 0) loss0[0] = 0.f;
    const int wave = threadIdx.x >> 6, lane = threadIdx.x & 63;
    const int row = blockIdx.x * 4 + wave;           // 0..639
    const float* src = supp + (size_t)row * DD;
    unsigned short* dstTile = sPk + (size_t)(row >> 4) * TILESH;   // tile = b*NS+s
    const int fr = row & 15;

    float4 v[4][2];
    float ss = 0.f;
    #pragma unroll
    for (int it = 0; it < 4; ++it) {
        v[it][0] = *reinterpret_cast<const float4*>(src + it * 512 + lane * 8);
        v[it][1] = *reinterpret_cast<const float4*>(src + it * 512 + lane * 8 + 4);
        #pragma unroll
        for (int h = 0; h < 2; ++h)
            ss += v[it][h].x * v[it][h].x + v[it][h].y * v[it][h].y
                + v[it][h].z * v[it][h].z + v[it][h].w * v[it][h].w;
    }
    #pragma unroll
    for (int off = 32; off >= 1; off >>= 1) ss += __shfl_xor(ss, off, 64);
    const float rs = 1.0f / sqrtf(fmaxf(ss, 1e-16f));

    #pragma unroll
    for (int it = 0; it < 4; ++it) {
        uint4 pv;
        pv.x = cvtpk(v[it][0].x * rs, v[it][0].y * rs);
        pv.y = cvtpk(v[it][0].z * rs, v[it][0].w * rs);
        pv.z = cvtpk(v[it][1].x * rs, v[it][1].y * rs);
        pv.w = cvtpk(v[it][1].z * rs, v[it][1].w * rs);
        const int kk = it * 16 + (lane >> 2);   // k/32
        const int c  = lane & 3;                // (k%32)/8
        *reinterpret_cast<uint4*>(dstTile + kk * 512 + (c * 16 + fr) * 8) = pv;
    }
}

// One block per (b,q), 8 waves (R1's proven split-role skeleton, 32 VGPR class).
// Per K-half: all 512 threads stage 16x1024 query cols f32->bf16 into LDS
// (R1-verified pattern) -> bar -> waves 0..4 (=s) run the dual-acc K-loop with
// A from PACKED sPk (coalesced 1KB wave-loads, R6-verified; the R1 scatter is
// gone) and B from LDS. acc lives only in compute waves (8 regs) -> no spill.
// No barrier after K: wave s writes AND reads only distS[s]. R4 tail.
__global__ __launch_bounds__(512, 8) void
dist_dtw_pk2(const unsigned short* __restrict__ sPk, const float* __restrict__ query,
             const int* __restrict__ ys, float* __restrict__ out)
{
    __shared__ __align__(16) unsigned short sB[TT][LDH];   // 33024 B
    __shared__ float distS[NS][TT][TT];                    //  5120 B
    __shared__ float qq[16];
    __shared__ float tamv[12];

    const int tid  = threadIdx.x;
    const int blk  = blockIdx.x;          // b*128 + q
    const int wave = tid >> 6;            // 0..7 (0..4 = s)
    const int lane = tid & 63;
    const int fr   = lane & 15;
    const int quad = lane >> 4;

    const int qr = tid >> 5;              // staging row 0..15
    const int qc = tid & 31;              // float4 column base within half

    float4v acc0 = {0.f, 0.f, 0.f, 0.f}, acc1 = {0.f, 0.f, 0.f, 0.f};
    const unsigned short* sp =
        sPk + ((size_t)(blk >> 7) * NS + wave) * TILESH + lane * 8;

    #pragma unroll
    for (int h = 0; h < 2; ++h) {
        // ---- stage K-half h: 16 x 1024 cols, coalesced f32, reg sumsq ----
        {
            const float* qsrc = query + (size_t)(blk * TT + qr) * DD + h * 1024;
            float ss = 0.f;
            #pragma unroll
            for (int i = 0; i < 8; ++i) {
                float4 v = *reinterpret_cast<const float4*>(qsrc + (qc + i * 32) * 4);
                uint2 pv = { cvtpk(v.x, v.y), cvtpk(v.z, v.w) };
                *reinterpret_cast<uint2*>(&sB[qr][(qc + i * 32) * 4]) = pv;
                ss += v.x * v.x + v.y * v.y + v.z * v.z + v.w * v.w;
            }
            #pragma unroll
            for (int off = 16; off >= 1; off >>= 1) ss += __shfl_xor(ss, off, 32);
            if (qc == 0) { if (h == 0) qq[qr] = ss; else qq[qr] += ss; }
        }
        __syncthreads();

        // ---- K-loop half h: wave s, dual accumulators (R1-verified) ----
        if (wave < NS) {
            const unsigned short* a  = sp + (size_t)(h * 32) * 512;
            const unsigned short* bp = &sB[fr][quad * 8];
            #pragma unroll 8
            for (int k2 = 0; k2 < 32; k2 += 2) {
                short8 a0 = *reinterpret_cast<const short8*>(a + (size_t)k2 * 512);
                short8 a1 = *reinterpret_cast<const short8*>(a + (size_t)(k2 + 1) * 512);
                short8 b0 = *reinterpret_cast<const short8*>(bp + k2 * 32);
                short8 b1 = *reinterpret_cast<const short8*>(bp + k2 * 32 + 32);
                acc0 = __builtin_amdgcn_mfma_f32_16x16x32_bf16(a0, b0, acc0, 0, 0, 0);
                acc1 = __builtin_amdgcn_mfma_f32_16x16x32_bf16(a1, b1, acc1, 0, 0, 0);
            }
        }
        if (h == 0) __syncthreads();   // sB reads done before re-stage
    }

    // ---- epilogue: dist[s][l][m] = 1 - dot/||q_m|| (supp pre-normalized);
    //      no barrier needed: wave s writes distS[s], reads only distS[s] ----
    __syncthreads();   // qq half-1 update visible to all compute waves
    if (wave < NS) {
        float rq = 1.0f / sqrtf(fmaxf(qq[fr], 1e-16f));
        #pragma unroll
        for (int r = 0; r < 4; ++r) {
            int l = quad * 4 + r;
            distS[wave][l][fr] = 1.0f - (acc0[r] + acc1[r]) * rq;
        }
    }

    dtw_tail512(distS, tamv, tid, blk, ys, out);
}

extern "C" void kernel_launch(void* const* d_in, const int* in_sizes, int n_in,
                              void* d_out, int out_size, void* d_ws, size_t ws_size,
                              hipStream_t stream) {
    const float* supp  = (const float*)d_in[0];
    const float* query = (const float*)d_in[1];
    const int*   ys    = (const int*)d_in[2];
    float* out = (float*)d_out;

    // workspace: packed supp tiles only — 40 * 32768 shorts = 2.62 MB
    unsigned short* sPk = (unsigned short*)d_ws;

    pack_supp<<<NSROW / 4, 256, 0, stream>>>(supp, sPk, out);
    dist_dtw_pk2<<<NROW, 512, 0, stream>>>(sPk, query, ys, out);
}